// Round 19
// baseline (314.260 us; speedup 1.0000x reference)
//
#include <hip/hip_runtime.h>

typedef float f4_t __attribute__((ext_vector_type(4)));
typedef __bf16 bf8_t __attribute__((ext_vector_type(8)));
typedef __bf16 bf4_t __attribute__((ext_vector_type(4)));

#define MFMA16(a,b,c) __builtin_amdgcn_mfma_f32_16x16x32_bf16((a),(b),(c),0,0,0)

static constexpr float kScale = 0.17677669529663687f; // 1/sqrt(32)

// LDS-only barrier: lgkmcnt(0)+s_barrier keeps global loads/stores in flight.
__device__ __forceinline__ void bar_lds() {
  asm volatile("s_waitcnt lgkmcnt(0)" ::: "memory");
  __builtin_amdgcn_s_barrier();
}

// ---------------------------------------------------------------------------
// K0: fold router query through Wq1 and Wk1 -> q1t (bf16), c1 (f32).
// (r17 weight-stationary form)
// ---------------------------------------------------------------------------
__global__ __launch_bounds__(256) void k0_fold(
    const float* __restrict__ router, const float* __restrict__ Wq1,
    const float* __restrict__ bq1, const float* __restrict__ Wk1,
    const float* __restrict__ bk1, __bf16* __restrict__ q1t,
    float* __restrict__ c1)
{
  __shared__ float q1[8][132];
  const int t = threadIdx.x, b = blockIdx.x;
  {
    const int dp = t & 127, rh = t >> 7;
    float acc[4] = {0.f, 0.f, 0.f, 0.f};
#pragma unroll 4
    for (int e = 0; e < 128; ++e) {
      float wq = Wq1[e*128 + dp];
#pragma unroll
      for (int i = 0; i < 4; ++i)
        acc[i] += router[(rh*4 + i)*128 + e] * wq;
    }
#pragma unroll
    for (int i = 0; i < 4; ++i)
      q1[rh*4 + i][dp] = acc[i] + bq1[dp];
  }
  __syncthreads();
  {
    const int j = t & 31, h = j >> 3, r = j & 7;
    const int e = b*8 + (t >> 5);
    f4_t qv[8];
#pragma unroll
    for (int d4 = 0; d4 < 8; ++d4)
      qv[d4] = *(const f4_t*)&q1[r][h*32 + d4*4];
    float acc = 0.f;
#pragma unroll
    for (int d4 = 0; d4 < 8; ++d4) {
      f4_t wv = *(const f4_t*)(Wk1 + e*128 + h*32 + d4*4);
#pragma unroll
      for (int i = 0; i < 4; ++i) acc += qv[d4][i] * wv[i];
    }
    q1t[j*128 + e] = (__bf16)(acc * kScale);
  }
  if (b == 0 && t < 32) {
    int h = t >> 3, r = t & 7;
    float acc = 0.f;
    for (int d = 0; d < 32; ++d) acc += q1[r][h*32 + d] * bk1[h*32 + d];
    c1[t] = acc * kScale;
  }
}

// ---------------------------------------------------------------------------
// K1: stage-1 attention partial reduction. One block = 256 rows; grid 2048.
// MEASURED (r12): ~76 us, ~5.7 TB/s — at roofline. Untouched.
// ---------------------------------------------------------------------------
__global__ __launch_bounds__(512) void k1_stage1(
    const float* __restrict__ Z, const __bf16* __restrict__ q1t_g,
    const float* __restrict__ c1_g, float* __restrict__ xap,
    float* __restrict__ lp, __bf16* __restrict__ xws)
{
  __shared__ __bf16 xb[64][136];   // x tile, row-major [pos][dim]
  __shared__ __bf16 xT[128][72];   // transposed   [dim][pos]
  __shared__ __bf16 PT[32][72];    // P            [j][pos]
  __shared__ float lds_l[32];

  const int tid = threadIdx.x;
  const int bid = blockIdx.x;                 // 2048 blocks, 256 rows each
  const float* xbase = Z + (size_t)bid * (256 * 128);
  __bf16* xwb = xws + (size_t)bid * (256 * 128);

  if (tid < 32) lds_l[tid] = 0.f;

  const int lane = tid & 63;
  const int w = tid >> 6;       // 8 waves
  const int lc = lane & 15;
  const int lg = lane >> 4;
  const int ms = w >> 2;        // j-tile (0..1)
  const int ns = w & 3;         // pos-tile (0..3)
  float c1v[4];
#pragma unroll
  for (int r2 = 0; r2 < 4; ++r2) c1v[r2] = c1_g[ms*16 + lg*4 + r2];
  bf8_t aq[4];
#pragma unroll
  for (int ks = 0; ks < 4; ++ks)
    aq[ks] = *(const bf8_t*)(q1t_g + (ms*16 + lc)*128 + ks*32 + lg*8);

  const f4_t fzero = {0.f, 0.f, 0.f, 0.f};
  f4_t accxa[2] = { fzero, fzero };   // D[dim][j]
  float Lacc[4] = {0.f, 0.f, 0.f, 0.f};

  const int srow = tid >> 4;            // 0..31
  const int sd0  = (tid & 15) << 3;     // dim base, 8 dims/lane

  f4_t zr[4];
#pragma unroll
  for (int i = 0; i < 2; ++i) {
    const float* p = xbase + (srow + 32*i)*128 + sd0;
    zr[i*2]   = __builtin_nontemporal_load((const f4_t*)p);
    zr[i*2+1] = __builtin_nontemporal_load((const f4_t*)(p + 4));
  }

  bar_lds();

  for (int tile = 0; tile < 4; ++tile) {
#pragma unroll
    for (int i = 0; i < 2; ++i) {
      int pos = srow + 32*i;
      f4_t v0 = zr[i*2], v1 = zr[i*2+1];
      bf8_t b8 = { (__bf16)v0.x, (__bf16)v0.y, (__bf16)v0.z, (__bf16)v0.w,
                   (__bf16)v1.x, (__bf16)v1.y, (__bf16)v1.z, (__bf16)v1.w };
      *(bf8_t*)&xb[pos][sd0] = b8;
      *(bf8_t*)(xwb + (tile*64 + pos)*128 + sd0) = b8;
    }
    bar_lds();                                          // B1

    if (tile < 3) {
      const float* xt = xbase + (tile + 1) * (64 * 128);
#pragma unroll
      for (int i = 0; i < 2; ++i) {
        const float* p = xt + (srow + 32*i)*128 + sd0;
        zr[i*2]   = __builtin_nontemporal_load((const f4_t*)p);
        zr[i*2+1] = __builtin_nontemporal_load((const f4_t*)(p + 4));
      }
    }

    // transpose xb -> xT
#pragma unroll
    for (int s = 0; s < 2; ++s) {
      int u = tid + s*512;
      int dim = u & 127, pb = (u >> 7) << 3;
      bf8_t t8;
#pragma unroll
      for (int p = 0; p < 8; ++p) t8[p] = xb[pb + p][dim];
      *(bf8_t*)&xT[dim][pb] = t8;
    }
    // scores
    f4_t sacc = fzero;
#pragma unroll
    for (int ks = 0; ks < 4; ++ks) {
      bf8_t b = *(const bf8_t*)&xb[ns*16 + lc][ks*32 + lg*8];
      sacc = MFMA16(aq[ks], b, sacc);
    }
    const int posn = ns*16 + lc;
#pragma unroll
    for (int r2 = 0; r2 < 4; ++r2) {
      float p = __expf(sacc[r2] + c1v[r2]);
      Lacc[r2] += p;
      PT[ms*16 + lg*4 + r2][posn] = (__bf16)p;
    }
    bar_lds();                                          // B2

    // PV (swapped): D[dim][j]
#pragma unroll
    for (int nt = 0; nt < 2; ++nt) {
      const int dimt = (ns << 1) + nt;
#pragma unroll
      for (int ks = 0; ks < 2; ++ks) {
        bf8_t a = *(const bf8_t*)&xT[dimt*16 + lc][ks*32 + lg*8];
        bf8_t b = *(const bf8_t*)&PT[ms*16 + lc][ks*32 + lg*8];
        accxa[nt] = MFMA16(a, b, accxa[nt]);
      }
    }
  }

#pragma unroll
  for (int r2 = 0; r2 < 4; ++r2) {
    float v = Lacc[r2];
    v += __shfl_xor(v, 1);
    v += __shfl_xor(v, 2);
    v += __shfl_xor(v, 4);
    v += __shfl_xor(v, 8);
    if (lc == 0) atomicAdd(&lds_l[ms*16 + lg*4 + r2], v);
  }
  bar_lds();

  float* xo = xap + (size_t)bid * 4096;
  const int jrow = ms*16 + lc;
#pragma unroll
  for (int nt = 0; nt < 2; ++nt) {
    const int dim0 = ((ns << 1) + nt)*16 + lg*4;
    *(f4_t*)(xo + jrow*128 + dim0) = accxa[nt];
  }
  if (tid < 32) lp[bid*32 + tid] = lds_l[tid];
}

// ---------------------------------------------------------------------------
// K2': fused K1b prologue (weight-stationary, conflict-free padding) + r10
// main loop. Output stores via L2 (NT removed: NT partial-line f4 stores
// caused 1.48x HBM write amplification — 397MB for a 268MB output).
// ---------------------------------------------------------------------------
__global__ __launch_bounds__(512) void k2_stage2(
    const __bf16* __restrict__ xws, const float* __restrict__ xap,
    const float* __restrict__ lp,
    const float* __restrict__ Wv1, const float* __restrict__ bv1,
    const float* __restrict__ Wo1, const float* __restrict__ bo1,
    const float* __restrict__ Wk2, const float* __restrict__ bk2,
    const float* __restrict__ Wv2, const float* __restrict__ bv2,
    const float* __restrict__ Wq2, const float* __restrict__ bq2,
    const float* __restrict__ Wo2, const float* __restrict__ bo2,
    const float* __restrict__ gamma, const float* __restrict__ beta,
    float* __restrict__ out)
{
  // LDS plan (64896 B, 2 blocks/CU):
  //  [0,34816)     xb [128][136] bf16 (main loop)
  //    prologue aliases (phase-disjoint):
  //      xaT   f32[128][33] @0     (16896)  live ph0-1
  //      out1T f32[128][13] @16896 (6656)   live ph1-2
  //      rbT   f32[128][13] @23552 (6656)   live ph2-3
  //      k2s   f32[8][140]  @0     (4480)   live ph3-4 (xaT dead)
  //      v2s   f32[8][140]  @4480  (4480)
  //  [34816,45056) P2  [128][40] bf16
  //  [45056,53760) ktL [32][136] bf16
  //  [53760,64000) vtL [128][40] bf16
  //  [64000,64128) c2L f32[32]
  //  [64128,64256) invl f32[32]
  __shared__ __align__(16) char smem[64896];
  __bf16 (*xb)[136]  = (__bf16 (*)[136])(smem);
  __bf16 (*P2)[40]   = (__bf16 (*)[40])(smem + 34816);
  __bf16 (*ktL)[136] = (__bf16 (*)[136])(smem + 45056);
  __bf16 (*vtL)[40]  = (__bf16 (*)[40])(smem + 53760);
  float* c2L  = (float*)(smem + 64000);
  float* invl = (float*)(smem + 64128);
  float (*xaT)[33]   = (float (*)[33])(smem);
  float (*out1T)[13] = (float (*)[13])(smem + 16896);
  float (*rbT)[13]   = (float (*)[13])(smem + 23552);
  float (*k2s)[140]  = (float (*)[140])(smem);
  float (*v2s)[140]  = (float (*)[140])(smem + 4480);

  const int tid = threadIdx.x;
  const int blk = blockIdx.x;               // 512 blocks, 8 chunks each
  const int batch = blk >> 1;               // 2 blocks per batch

  const int lane = tid & 63;
  const int w = tid >> 6;    // 8 waves
  const int lc = lane & 15;
  const int lg = lane >> 4;

  int spos[4], sd[4];
#pragma unroll
  for (int j = 0; j < 4; ++j) {
    int c = lane + j*64;
    spos[j] = w*16 + (c >> 4);
    sd[j]   = (c & 15) << 3;
  }
  const size_t base0 = (size_t)blk * 8 * 16384;   // 8 chunks x 128 x 128
  // chunk-0 prefetch first: HBM latency hides under the prologue
  uint4 zx[4];
#pragma unroll
  for (int j = 0; j < 4; ++j)
    zx[j] = *(const uint4*)(xws + base0 + spos[j]*128 + sd[j]);

  // ---- fused weight-stationary prologue ----
  // phase 0: xaT[e][j] = sum of 8 partials; invl
#pragma unroll
  for (int i = 0; i < 8; ++i) {
    int idx = tid + i*512;
    int j = idx >> 7, e = idx & 127;
    float s = 0.f;
#pragma unroll
    for (int k = 0; k < 8; ++k)
      s += xap[(size_t)(batch*8 + k) * 4096 + idx];
    xaT[e][j] = s;
  }
  if (tid < 32) {
    float s = 0.f;
#pragma unroll
    for (int k = 0; k < 8; ++k) s += lp[(batch*8 + k)*32 + tid];
    invl[tid] = 1.f / s;
  }
  bar_lds();
  // phase 1: out1T[hd][r] (2 r-chains/thread)
  {
    const int hd = tid & 127, rh = tid >> 7, h = hd >> 5;
    const int j0 = h*8 + rh*2;
    float acc[2] = {0.f, 0.f};
#pragma unroll 4
    for (int e = 0; e < 128; ++e) {
      float wv = Wv1[e*128 + hd];
      acc[0] += xaT[e][j0] * wv;
      acc[1] += xaT[e][j0 + 1] * wv;
    }
    float bv = bv1[hd];
    out1T[hd][rh*2]     = acc[0] * invl[j0] + bv;
    out1T[hd][rh*2 + 1] = acc[1] * invl[j0 + 1] + bv;
  }
  bar_lds();
  // phase 2: rbT[e2][r]
  {
    const int e2 = tid & 127, rh = tid >> 7;
    float acc[2] = {0.f, 0.f};
#pragma unroll 4
    for (int hd = 0; hd < 128; ++hd) {
      float wo = Wo1[hd*128 + e2];
      acc[0] += out1T[hd][rh*2] * wo;
      acc[1] += out1T[hd][rh*2 + 1] * wo;
    }
    float bo = bo1[e2];
    rbT[e2][rh*2]     = acc[0] + bo;
    rbT[e2][rh*2 + 1] = acc[1] + bo;
  }
  bar_lds();
  // phase 3: k2s/v2s[r][hd] (4 r-chains/thread, 2 matrices)
  {
    const int hd = tid & 127, q = tid >> 7;
    const int sel = q >> 1, r0 = (q & 1) * 4;
    const float* W  = sel ? Wv2 : Wk2;
    const float* bb = sel ? bv2 : bk2;
    float (*dst)[140] = sel ? v2s : k2s;
    float bbv = bb[hd];
    float acc[4] = {bbv, bbv, bbv, bbv};
#pragma unroll 4
    for (int e = 0; e < 128; ++e) {
      float wv = W[e*128 + hd];
#pragma unroll
      for (int i = 0; i < 4; ++i) acc[i] += rbT[e][r0 + i] * wv;
    }
#pragma unroll
    for (int i = 0; i < 4; ++i) dst[r0 + i][hd] = acc[i];
  }
  bar_lds();
  // phase 4: fold -> ktL, vtL, c2L (f4 hoists, 8 e/thread)
  {
    const int j = tid & 31, h = j >> 3, r = j & 7;
    const int esub = tid >> 5;             // 0..15
    f4_t k2v[8], v2v[8];
#pragma unroll
    for (int d4 = 0; d4 < 8; ++d4) {
      k2v[d4] = *(const f4_t*)&k2s[r][h*32 + d4*4];
      v2v[d4] = *(const f4_t*)&v2s[r][h*32 + d4*4];
    }
#pragma unroll
    for (int ei = 0; ei < 8; ++ei) {
      const int e = esub + ei*16;
      float acck = 0.f, accv = 0.f;
#pragma unroll
      for (int d4 = 0; d4 < 8; ++d4) {
        f4_t wq = *(const f4_t*)(Wq2 + e*128 + h*32 + d4*4);
#pragma unroll
        for (int i = 0; i < 4; ++i) {
          acck += wq[i] * k2v[d4][i];
          accv += v2v[d4][i] * Wo2[(h*32 + d4*4 + i)*128 + e];
        }
      }
      ktL[j][e] = (__bf16)(acck * kScale);
      vtL[e][j] = (__bf16)accv;
    }
    if (tid < 32) {
      int hh = tid >> 3, rr = tid & 7;
      float acc = 0.f;
#pragma unroll
      for (int d = 0; d < 32; ++d) acc += bq2[hh*32 + d] * k2s[rr][hh*32 + d];
      c2L[tid] = acc * kScale;
    }
  }
  bar_lds();   // ktL/vtL/c2L ready; xb region free

  // ---- main loop (r10 form; kt/vfrag/c2 from LDS) ----
  float c2v[2] = { c2L[lc], c2L[16 + lc] };
  f4_t bo2v[8], gv[8], bv[8];
#pragma unroll
  for (int nt = 0; nt < 8; ++nt) {
    int dd = nt*16 + lg*4;
    bo2v[nt] = *(const f4_t*)(bo2 + dd);
    gv[nt]   = *(const f4_t*)(gamma + dd);
    bv[nt]   = *(const f4_t*)(beta + dd);
  }
  bf8_t vfrag[8];
#pragma unroll
  for (int nt = 0; nt < 8; ++nt)
    vfrag[nt] = *(const bf8_t*)&vtL[nt*16 + lc][lg*8];

  const f4_t fzero = {0.f, 0.f, 0.f, 0.f};

  for (int c = 0; c < 8; ++c) {
    const size_t cb = base0 + (size_t)c * 16384;
#pragma unroll
    for (int j = 0; j < 4; ++j)
      *(uint4*)&xb[spos[j]][sd[j]] = zx[j];
    if (c < 7) {
#pragma unroll
      for (int j = 0; j < 4; ++j)
        zx[j] = *(const uint4*)(xws + cb + 16384 + spos[j]*128 + sd[j]);
    }

    f4_t sacc[2] = { fzero, fzero };
#pragma unroll
    for (int ks = 0; ks < 4; ++ks) {
      bf8_t a = *(const bf8_t*)&xb[w*16 + lc][ks*32 + lg*8];
#pragma unroll
      for (int nt = 0; nt < 2; ++nt) {
        bf8_t b = *(const bf8_t*)&ktL[nt*16 + lc][ks*32 + lg*8];
        sacc[nt] = MFMA16(a, b, sacc[nt]);
      }
    }
#pragma unroll
    for (int nt = 0; nt < 2; ++nt) {
#pragma unroll
      for (int r2 = 0; r2 < 4; ++r2) {
        float p = __expf(sacc[nt][r2] + c2v[nt]);
        float sum = p;
        sum += __shfl_xor(sum, 1);
        sum += __shfl_xor(sum, 2);
        sum += __shfl_xor(sum, 4);
        P2[w*16 + lg*4 + r2][nt*16 + lc] = (__bf16)(p * __builtin_amdgcn_rcpf(sum));
      }
    }

    bf8_t pf = *(const bf8_t*)&P2[w*16 + lc][lg*8];
    f4_t racc[8];
#pragma unroll
    for (int nt = 0; nt < 8; ++nt)
      racc[nt] = MFMA16(vfrag[nt], pf, fzero);

    const int pos = w*16 + lc;
    float s1 = 0.f, s2 = 0.f;
#pragma unroll
    for (int nt = 0; nt < 8; ++nt) {
      bf4_t xq = *(const bf4_t*)&xb[pos][nt*16 + lg*4];
#pragma unroll
      for (int r = 0; r < 4; ++r) {
        float tv = racc[nt][r] + bo2v[nt][r] + (float)xq[r];
        racc[nt][r] = tv;
        s1 += tv; s2 += tv*tv;
      }
    }
    s1 += __shfl_xor(s1, 16); s1 += __shfl_xor(s1, 32);
    s2 += __shfl_xor(s2, 16); s2 += __shfl_xor(s2, 32);
    float mean = s1 * (1.f/128.f);
    float var = s2 * (1.f/128.f) - mean*mean;
    float rstd = rsqrtf(var + 1e-5f);

    float* y = out + cb + (size_t)pos*128;
#pragma unroll
    for (int nt = 0; nt < 8; ++nt) {
      f4_t o;
#pragma unroll
      for (int r = 0; r < 4; ++r)
        o[r] = (racc[nt][r] - mean) * rstd * gv[nt][r] + bv[nt][r];
      *(f4_t*)(y + nt*16 + lg*4) = o;   // through L2: full-line writeback
    }
  }
}

// ---------------------------------------------------------------------------
extern "C" void kernel_launch(void* const* d_in, const int* in_sizes, int n_in,
                              void* d_out, int out_size, void* d_ws, size_t ws_size,
                              hipStream_t stream)
{
  const float* Z     = (const float*)d_in[0];
  const float* router= (const float*)d_in[1];
  const float* Wq1   = (const float*)d_in[2];
  const float* bq1   = (const float*)d_in[3];
  const float* Wk1   = (const float*)d_in[4];
  const float* bk1   = (const float*)d_in[5];
  const float* Wv1   = (const float*)d_in[6];
  const float* bv1   = (const float*)d_in[7];
  const float* Wo1   = (const float*)d_in[8];
  const float* bo1   = (const float*)d_in[9];
  const float* Wq2   = (const float*)d_in[10];
  const float* bq2   = (const float*)d_in[11];
  const float* Wk2   = (const float*)d_in[12];
  const float* bk2   = (const float*)d_in[13];
  const float* Wv2   = (const float*)d_in[14];
  const float* bv2   = (const float*)d_in[15];
  const float* Wo2   = (const float*)d_in[16];
  const float* bo2   = (const float*)d_in[17];
  const float* gamma = (const float*)d_in[18];
  const float* beta  = (const float*)d_in[19];
  float* out = (float*)d_out;

  char* base = (char*)d_ws;
  __bf16* q1tb = (__bf16*)(base);                  // 8 KB
  float*  c1   = (float*)(base + 8192);            // 128 B
  float*  lp   = (float*)(base + 65536);           // 256 KB (2048*32*4)
  float*  xap  = (float*)(base + (1u<<20));        // 32 MB (2048*4096*4)
  __bf16* xws  = (__bf16*)(base + (40u<<20));      // 128 MB (bf16 Z)
  (void)in_sizes; (void)n_in; (void)out_size; (void)ws_size;

  k0_fold<<<dim3(16), dim3(256), 0, stream>>>(router, Wq1, bq1, Wk1, bk1, q1tb, c1);
  k1_stage1<<<dim3(2048), dim3(512), 0, stream>>>(Z, q1tb, c1, xap, lp, xws);
  k2_stage2<<<dim3(512), dim3(512), 0, stream>>>(xws, xap, lp,
                                                 Wv1, bv1, Wo1, bo1,
                                                 Wk2, bk2, Wv2, bv2,
                                                 Wq2, bq2, Wo2,
                                                 bo2, gamma, beta, out);
}

// Round 20
// 265.525 us; speedup vs baseline: 1.1835x; 1.1835x over previous
//
#include <hip/hip_runtime.h>

typedef float f4_t __attribute__((ext_vector_type(4)));
typedef __bf16 bf8_t __attribute__((ext_vector_type(8)));
typedef __bf16 bf4_t __attribute__((ext_vector_type(4)));

#define MFMA16(a,b,c) __builtin_amdgcn_mfma_f32_16x16x32_bf16((a),(b),(c),0,0,0)

static constexpr float kScale = 0.17677669529663687f; // 1/sqrt(32)

// LDS-only barrier: lgkmcnt(0)+s_barrier keeps global loads/stores in flight.
__device__ __forceinline__ void bar_lds() {
  asm volatile("s_waitcnt lgkmcnt(0)" ::: "memory");
  __builtin_amdgcn_s_barrier();
}
// Full barrier: drains own global stores before the barrier so after it,
// every thread's stores are L2-visible to the whole block.
__device__ __forceinline__ void bar_full() {
  asm volatile("s_waitcnt vmcnt(0) lgkmcnt(0)" ::: "memory");
  __builtin_amdgcn_s_barrier();
}

// ---------------------------------------------------------------------------
// K0: fold router query through Wq1 and Wk1 -> q1t (bf16), c1 (f32).
// (r17 weight-stationary form)
// ---------------------------------------------------------------------------
__global__ __launch_bounds__(256) void k0_fold(
    const float* __restrict__ router, const float* __restrict__ Wq1,
    const float* __restrict__ bq1, const float* __restrict__ Wk1,
    const float* __restrict__ bk1, __bf16* __restrict__ q1t,
    float* __restrict__ c1)
{
  __shared__ float q1[8][132];
  const int t = threadIdx.x, b = blockIdx.x;
  {
    const int dp = t & 127, rh = t >> 7;
    float acc[4] = {0.f, 0.f, 0.f, 0.f};
#pragma unroll 4
    for (int e = 0; e < 128; ++e) {
      float wq = Wq1[e*128 + dp];
#pragma unroll
      for (int i = 0; i < 4; ++i)
        acc[i] += router[(rh*4 + i)*128 + e] * wq;
    }
#pragma unroll
    for (int i = 0; i < 4; ++i)
      q1[rh*4 + i][dp] = acc[i] + bq1[dp];
  }
  __syncthreads();
  {
    const int j = t & 31, h = j >> 3, r = j & 7;
    const int e = b*8 + (t >> 5);
    f4_t qv[8];
#pragma unroll
    for (int d4 = 0; d4 < 8; ++d4)
      qv[d4] = *(const f4_t*)&q1[r][h*32 + d4*4];
    float acc = 0.f;
#pragma unroll
    for (int d4 = 0; d4 < 8; ++d4) {
      f4_t wv = *(const f4_t*)(Wk1 + e*128 + h*32 + d4*4);
#pragma unroll
      for (int i = 0; i < 4; ++i) acc += qv[d4][i] * wv[i];
    }
    q1t[j*128 + e] = (__bf16)(acc * kScale);
  }
  if (b == 0 && t < 32) {
    int h = t >> 3, r = t & 7;
    float acc = 0.f;
    for (int d = 0; d < 32; ++d) acc += q1[r][h*32 + d] * bk1[h*32 + d];
    c1[t] = acc * kScale;
  }
}

// ---------------------------------------------------------------------------
// K1: stage-1 attention partial reduction. One block = 256 rows; grid 2048.
// MEASURED (r12): ~76 us, ~5.7 TB/s — at roofline. Untouched.
// ---------------------------------------------------------------------------
__global__ __launch_bounds__(512) void k1_stage1(
    const float* __restrict__ Z, const __bf16* __restrict__ q1t_g,
    const float* __restrict__ c1_g, float* __restrict__ xap,
    float* __restrict__ lp, __bf16* __restrict__ xws)
{
  __shared__ __bf16 xb[64][136];   // x tile, row-major [pos][dim]
  __shared__ __bf16 xT[128][72];   // transposed   [dim][pos]
  __shared__ __bf16 PT[32][72];    // P            [j][pos]
  __shared__ float lds_l[32];

  const int tid = threadIdx.x;
  const int bid = blockIdx.x;                 // 2048 blocks, 256 rows each
  const float* xbase = Z + (size_t)bid * (256 * 128);
  __bf16* xwb = xws + (size_t)bid * (256 * 128);

  if (tid < 32) lds_l[tid] = 0.f;

  const int lane = tid & 63;
  const int w = tid >> 6;       // 8 waves
  const int lc = lane & 15;
  const int lg = lane >> 4;
  const int ms = w >> 2;        // j-tile (0..1)
  const int ns = w & 3;         // pos-tile (0..3)
  float c1v[4];
#pragma unroll
  for (int r2 = 0; r2 < 4; ++r2) c1v[r2] = c1_g[ms*16 + lg*4 + r2];
  bf8_t aq[4];
#pragma unroll
  for (int ks = 0; ks < 4; ++ks)
    aq[ks] = *(const bf8_t*)(q1t_g + (ms*16 + lc)*128 + ks*32 + lg*8);

  const f4_t fzero = {0.f, 0.f, 0.f, 0.f};
  f4_t accxa[2] = { fzero, fzero };   // D[dim][j]
  float Lacc[4] = {0.f, 0.f, 0.f, 0.f};

  const int srow = tid >> 4;            // 0..31
  const int sd0  = (tid & 15) << 3;     // dim base, 8 dims/lane

  f4_t zr[4];
#pragma unroll
  for (int i = 0; i < 2; ++i) {
    const float* p = xbase + (srow + 32*i)*128 + sd0;
    zr[i*2]   = __builtin_nontemporal_load((const f4_t*)p);
    zr[i*2+1] = __builtin_nontemporal_load((const f4_t*)(p + 4));
  }

  bar_lds();

  for (int tile = 0; tile < 4; ++tile) {
#pragma unroll
    for (int i = 0; i < 2; ++i) {
      int pos = srow + 32*i;
      f4_t v0 = zr[i*2], v1 = zr[i*2+1];
      bf8_t b8 = { (__bf16)v0.x, (__bf16)v0.y, (__bf16)v0.z, (__bf16)v0.w,
                   (__bf16)v1.x, (__bf16)v1.y, (__bf16)v1.z, (__bf16)v1.w };
      *(bf8_t*)&xb[pos][sd0] = b8;
      *(bf8_t*)(xwb + (tile*64 + pos)*128 + sd0) = b8;
    }
    bar_lds();                                          // B1

    if (tile < 3) {
      const float* xt = xbase + (tile + 1) * (64 * 128);
#pragma unroll
      for (int i = 0; i < 2; ++i) {
        const float* p = xt + (srow + 32*i)*128 + sd0;
        zr[i*2]   = __builtin_nontemporal_load((const f4_t*)p);
        zr[i*2+1] = __builtin_nontemporal_load((const f4_t*)(p + 4));
      }
    }

    // transpose xb -> xT
#pragma unroll
    for (int s = 0; s < 2; ++s) {
      int u = tid + s*512;
      int dim = u & 127, pb = (u >> 7) << 3;
      bf8_t t8;
#pragma unroll
      for (int p = 0; p < 8; ++p) t8[p] = xb[pb + p][dim];
      *(bf8_t*)&xT[dim][pb] = t8;
    }
    // scores
    f4_t sacc = fzero;
#pragma unroll
    for (int ks = 0; ks < 4; ++ks) {
      bf8_t b = *(const bf8_t*)&xb[ns*16 + lc][ks*32 + lg*8];
      sacc = MFMA16(aq[ks], b, sacc);
    }
    const int posn = ns*16 + lc;
#pragma unroll
    for (int r2 = 0; r2 < 4; ++r2) {
      float p = __expf(sacc[r2] + c1v[r2]);
      Lacc[r2] += p;
      PT[ms*16 + lg*4 + r2][posn] = (__bf16)p;
    }
    bar_lds();                                          // B2

    // PV (swapped): D[dim][j]
#pragma unroll
    for (int nt = 0; nt < 2; ++nt) {
      const int dimt = (ns << 1) + nt;
#pragma unroll
      for (int ks = 0; ks < 2; ++ks) {
        bf8_t a = *(const bf8_t*)&xT[dimt*16 + lc][ks*32 + lg*8];
        bf8_t b = *(const bf8_t*)&PT[ms*16 + lc][ks*32 + lg*8];
        accxa[nt] = MFMA16(a, b, accxa[nt]);
      }
    }
  }

#pragma unroll
  for (int r2 = 0; r2 < 4; ++r2) {
    float v = Lacc[r2];
    v += __shfl_xor(v, 1);
    v += __shfl_xor(v, 2);
    v += __shfl_xor(v, 4);
    v += __shfl_xor(v, 8);
    if (lc == 0) atomicAdd(&lds_l[ms*16 + lg*4 + r2], v);
  }
  bar_lds();

  float* xo = xap + (size_t)bid * 4096;
  const int jrow = ms*16 + lc;
#pragma unroll
  for (int nt = 0; nt < 2; ++nt) {
    const int dim0 = ((ns << 1) + nt)*16 + lg*4;
    *(f4_t*)(xo + jrow*128 + dim0) = accxa[nt];
  }
  if (tid < 32) lp[bid*32 + tid] = lds_l[tid];
}

// ---------------------------------------------------------------------------
// K2'': fused prologue writes kt2/vt2 to GLOBAL workspace (both blocks of a
// batch write identical bytes — benign; each reads back its own XCD-L2 copy
// after bar_full). No persistent kt/vt LDS -> 45.3 KB -> 3 blocks/CU (the
// r18 fusion lost 33% occupancy to 64.5 KB). Main loop = r13 form: kt/vT
// fragments per-use from global (L1-hot), biases per-use (VGPR diet for the
// 24-wave/CU budget), NT stores (measured faster than L2 path in r19).
// ---------------------------------------------------------------------------
__global__ __launch_bounds__(512) void k2_stage2(
    const __bf16* __restrict__ xws, const float* __restrict__ xap,
    const float* __restrict__ lp,
    const float* __restrict__ Wv1, const float* __restrict__ bv1,
    const float* __restrict__ Wo1, const float* __restrict__ bo1,
    const float* __restrict__ Wk2, const float* __restrict__ bk2,
    const float* __restrict__ Wv2, const float* __restrict__ bv2,
    const float* __restrict__ Wq2, const float* __restrict__ bq2,
    const float* __restrict__ Wo2, const float* __restrict__ bo2,
    const float* __restrict__ gamma, const float* __restrict__ beta,
    __bf16* kt2g, __bf16* vt2g, float* __restrict__ out)
{
  // LDS (45312 B -> 3 blocks/CU):
  //  [0,34816)     xb [128][136] bf16 (main loop)
  //    prologue aliases (phase-disjoint):
  //      xaT   f32[128][33] @0     live ph0-1
  //      out1T f32[128][13] @16896 live ph1-2
  //      rbT   f32[128][13] @23552 live ph2-3
  //      k2s   f32[8][140]  @0     live ph3-4 (xaT dead)
  //      v2s   f32[8][140]  @4480
  //  [34816,45056) P2 [128][40] bf16
  //  [45056,45184) c2L f32[32]
  //  [45184,45312) invl f32[32]
  __shared__ __align__(16) char smem[45312];
  __bf16 (*xb)[136]  = (__bf16 (*)[136])(smem);
  __bf16 (*P2)[40]   = (__bf16 (*)[40])(smem + 34816);
  float* c2L  = (float*)(smem + 45056);
  float* invl = (float*)(smem + 45184);
  float (*xaT)[33]   = (float (*)[33])(smem);
  float (*out1T)[13] = (float (*)[13])(smem + 16896);
  float (*rbT)[13]   = (float (*)[13])(smem + 23552);
  float (*k2s)[140]  = (float (*)[140])(smem);
  float (*v2s)[140]  = (float (*)[140])(smem + 4480);

  const int tid = threadIdx.x;
  const int blk = blockIdx.x;               // 512 blocks, 8 chunks each
  const int batch = blk >> 1;               // 2 blocks per batch

  const int lane = tid & 63;
  const int w = tid >> 6;    // 8 waves
  const int lc = lane & 15;
  const int lg = lane >> 4;

  int spos[4], sd[4];
#pragma unroll
  for (int j = 0; j < 4; ++j) {
    int c = lane + j*64;
    spos[j] = w*16 + (c >> 4);
    sd[j]   = (c & 15) << 3;
  }
  const size_t base0 = (size_t)blk * 8 * 16384;   // 8 chunks x 128 x 128
  // chunk-0 prefetch first: HBM latency hides under the prologue
  uint4 zx[4];
#pragma unroll
  for (int j = 0; j < 4; ++j)
    zx[j] = *(const uint4*)(xws + base0 + spos[j]*128 + sd[j]);

  // ---- fused weight-stationary prologue ----
  // phase 0: xaT[e][j] = sum of 8 partials; invl
#pragma unroll
  for (int i = 0; i < 8; ++i) {
    int idx = tid + i*512;
    int j = idx >> 7, e = idx & 127;
    float s = 0.f;
#pragma unroll
    for (int k = 0; k < 8; ++k)
      s += xap[(size_t)(batch*8 + k) * 4096 + idx];
    xaT[e][j] = s;
  }
  if (tid < 32) {
    float s = 0.f;
#pragma unroll
    for (int k = 0; k < 8; ++k) s += lp[(batch*8 + k)*32 + tid];
    invl[tid] = 1.f / s;
  }
  bar_lds();
  // phase 1: out1T[hd][r] (2 r-chains/thread)
  {
    const int hd = tid & 127, rh = tid >> 7, h = hd >> 5;
    const int j0 = h*8 + rh*2;
    float acc[2] = {0.f, 0.f};
#pragma unroll 4
    for (int e = 0; e < 128; ++e) {
      float wv = Wv1[e*128 + hd];
      acc[0] += xaT[e][j0] * wv;
      acc[1] += xaT[e][j0 + 1] * wv;
    }
    float bv = bv1[hd];
    out1T[hd][rh*2]     = acc[0] * invl[j0] + bv;
    out1T[hd][rh*2 + 1] = acc[1] * invl[j0 + 1] + bv;
  }
  bar_lds();
  // phase 2: rbT[e2][r]
  {
    const int e2 = tid & 127, rh = tid >> 7;
    float acc[2] = {0.f, 0.f};
#pragma unroll 4
    for (int hd = 0; hd < 128; ++hd) {
      float wo = Wo1[hd*128 + e2];
      acc[0] += out1T[hd][rh*2] * wo;
      acc[1] += out1T[hd][rh*2 + 1] * wo;
    }
    float bo = bo1[e2];
    rbT[e2][rh*2]     = acc[0] + bo;
    rbT[e2][rh*2 + 1] = acc[1] + bo;
  }
  bar_lds();
  // phase 3: k2s/v2s[r][hd] (4 r-chains/thread, 2 matrices)
  {
    const int hd = tid & 127, q = tid >> 7;
    const int sel = q >> 1, r0 = (q & 1) * 4;
    const float* W  = sel ? Wv2 : Wk2;
    const float* bb = sel ? bv2 : bk2;
    float (*dst)[140] = sel ? v2s : k2s;
    float bbv = bb[hd];
    float acc[4] = {bbv, bbv, bbv, bbv};
#pragma unroll 4
    for (int e = 0; e < 128; ++e) {
      float wv = W[e*128 + hd];
#pragma unroll
      for (int i = 0; i < 4; ++i) acc[i] += rbT[e][r0 + i] * wv;
    }
#pragma unroll
    for (int i = 0; i < 4; ++i) dst[r0 + i][hd] = acc[i];
  }
  bar_lds();
  // phase 4: fold -> kt2g/vt2g (GLOBAL, per-batch; duplicate identical
  // writes from the 2 blocks of a batch are benign) + c2L (LDS)
  {
    const int j = tid & 31, h = j >> 3, r = j & 7;
    const int esub = tid >> 5;             // 0..15
    f4_t k2v[8], v2v[8];
#pragma unroll
    for (int d4 = 0; d4 < 8; ++d4) {
      k2v[d4] = *(const f4_t*)&k2s[r][h*32 + d4*4];
      v2v[d4] = *(const f4_t*)&v2s[r][h*32 + d4*4];
    }
#pragma unroll
    for (int ei = 0; ei < 8; ++ei) {
      const int e = esub + ei*16;
      float acck = 0.f, accv = 0.f;
#pragma unroll
      for (int d4 = 0; d4 < 8; ++d4) {
        f4_t wq = *(const f4_t*)(Wq2 + e*128 + h*32 + d4*4);
#pragma unroll
        for (int i = 0; i < 4; ++i) {
          acck += wq[i] * k2v[d4][i];
          accv += v2v[d4][i] * Wo2[(h*32 + d4*4 + i)*128 + e];
        }
      }
      kt2g[(size_t)batch*4096 + j*128 + e] = (__bf16)(acck * kScale);
      vt2g[(size_t)batch*4096 + e*32 + j] = (__bf16)accv;
    }
    if (tid < 32) {
      int hh = tid >> 3, rr = tid & 7;
      float acc = 0.f;
#pragma unroll
      for (int d = 0; d < 32; ++d) acc += bq2[hh*32 + d] * k2s[rr][hh*32 + d];
      c2L[tid] = acc * kScale;
    }
  }
  bar_full();  // drain kt2g/vt2g stores (L2-visible to whole block) + LDS

  // ---- main loop (r13 form: kt/vT per-use from global, L1-hot) ----
  const __bf16* ktb = kt2g + (size_t)batch * 4096;
  const __bf16* vtb = vt2g + (size_t)batch * 4096;
  float c2v[2] = { c2L[lc], c2L[16 + lc] };

  const f4_t fzero = {0.f, 0.f, 0.f, 0.f};

  for (int c = 0; c < 8; ++c) {
    const size_t cb = base0 + (size_t)c * 16384;
#pragma unroll
    for (int j = 0; j < 4; ++j)
      *(uint4*)&xb[spos[j]][sd[j]] = zx[j];
    if (c < 7) {
#pragma unroll
      for (int j = 0; j < 4; ++j)
        zx[j] = *(const uint4*)(xws + cb + 16384 + spos[j]*128 + sd[j]);
    }

    f4_t sacc[2] = { fzero, fzero };
#pragma unroll
    for (int ks = 0; ks < 4; ++ks) {
      bf8_t a = *(const bf8_t*)&xb[w*16 + lc][ks*32 + lg*8];
#pragma unroll
      for (int nt = 0; nt < 2; ++nt) {
        bf8_t b = *(const bf8_t*)(ktb + (nt*16 + lc)*128 + ks*32 + lg*8);
        sacc[nt] = MFMA16(a, b, sacc[nt]);
      }
    }
#pragma unroll
    for (int nt = 0; nt < 2; ++nt) {
#pragma unroll
      for (int r2 = 0; r2 < 4; ++r2) {
        float p = __expf(sacc[nt][r2] + c2v[nt]);
        float sum = p;
        sum += __shfl_xor(sum, 1);
        sum += __shfl_xor(sum, 2);
        sum += __shfl_xor(sum, 4);
        P2[w*16 + lg*4 + r2][nt*16 + lc] = (__bf16)(p * __builtin_amdgcn_rcpf(sum));
      }
    }

    bf8_t pf = *(const bf8_t*)&P2[w*16 + lc][lg*8];
    f4_t racc[8];
#pragma unroll
    for (int nt = 0; nt < 8; ++nt) {
      bf8_t vfr = *(const bf8_t*)(vtb + (nt*16 + lc)*32 + lg*8);
      racc[nt] = MFMA16(vfr, pf, fzero);
    }

    const int pos = w*16 + lc;
    float s1 = 0.f, s2 = 0.f;
#pragma unroll
    for (int nt = 0; nt < 8; ++nt) {
      bf4_t xq = *(const bf4_t*)&xb[pos][nt*16 + lg*4];
      f4_t bq = *(const f4_t*)(bo2 + nt*16 + lg*4);
#pragma unroll
      for (int r = 0; r < 4; ++r) {
        float tv = racc[nt][r] + bq[r] + (float)xq[r];
        racc[nt][r] = tv;
        s1 += tv; s2 += tv*tv;
      }
    }
    s1 += __shfl_xor(s1, 16); s1 += __shfl_xor(s1, 32);
    s2 += __shfl_xor(s2, 16); s2 += __shfl_xor(s2, 32);
    float mean = s1 * (1.f/128.f);
    float var = s2 * (1.f/128.f) - mean*mean;
    float rstd = rsqrtf(var + 1e-5f);

    float* y = out + cb + (size_t)pos*128;
#pragma unroll
    for (int nt = 0; nt < 8; ++nt) {
      f4_t gq = *(const f4_t*)(gamma + nt*16 + lg*4);
      f4_t bb = *(const f4_t*)(beta + nt*16 + lg*4);
      f4_t o;
#pragma unroll
      for (int r = 0; r < 4; ++r)
        o[r] = (racc[nt][r] - mean) * rstd * gq[r] + bb[r];
      __builtin_nontemporal_store(o, (f4_t*)(y + nt*16 + lg*4));
    }
  }
}

// ---------------------------------------------------------------------------
extern "C" void kernel_launch(void* const* d_in, const int* in_sizes, int n_in,
                              void* d_out, int out_size, void* d_ws, size_t ws_size,
                              hipStream_t stream)
{
  const float* Z     = (const float*)d_in[0];
  const float* router= (const float*)d_in[1];
  const float* Wq1   = (const float*)d_in[2];
  const float* bq1   = (const float*)d_in[3];
  const float* Wk1   = (const float*)d_in[4];
  const float* bk1   = (const float*)d_in[5];
  const float* Wv1   = (const float*)d_in[6];
  const float* bv1   = (const float*)d_in[7];
  const float* Wo1   = (const float*)d_in[8];
  const float* bo1   = (const float*)d_in[9];
  const float* Wq2   = (const float*)d_in[10];
  const float* bq2   = (const float*)d_in[11];
  const float* Wk2   = (const float*)d_in[12];
  const float* bk2   = (const float*)d_in[13];
  const float* Wv2   = (const float*)d_in[14];
  const float* bv2   = (const float*)d_in[15];
  const float* Wo2   = (const float*)d_in[16];
  const float* bo2   = (const float*)d_in[17];
  const float* gamma = (const float*)d_in[18];
  const float* beta  = (const float*)d_in[19];
  float* out = (float*)d_out;

  char* base = (char*)d_ws;
  __bf16* q1tb = (__bf16*)(base);                  // 8 KB
  float*  c1   = (float*)(base + 8192);            // 128 B
  float*  lp   = (float*)(base + 65536);           // 256 KB (2048*32*4)
  float*  xap  = (float*)(base + (1u<<20));        // 32 MB (2048*4096*4)
  __bf16* kt2b = (__bf16*)(base + (36u<<20));      // 2 MB
  __bf16* vt2b = (__bf16*)(base + (38u<<20));      // 2 MB
  __bf16* xws  = (__bf16*)(base + (40u<<20));      // 128 MB (bf16 Z)
  (void)in_sizes; (void)n_in; (void)out_size; (void)ws_size;

  k0_fold<<<dim3(16), dim3(256), 0, stream>>>(router, Wq1, bq1, Wk1, bk1, q1tb, c1);
  k1_stage1<<<dim3(2048), dim3(512), 0, stream>>>(Z, q1tb, c1, xap, lp, xws);
  k2_stage2<<<dim3(512), dim3(512), 0, stream>>>(xws, xap, lp,
                                                 Wv1, bv1, Wo1, bo1,
                                                 Wk2, bk2, Wv2, bv2,
                                                 Wq2, bq2, Wo2,
                                                 bo2, gamma, beta,
                                                 kt2b, vt2b, out);
}